// Round 14
// baseline (303.168 us; speedup 1.0000x reference)
//
#include <hip/hip_runtime.h>

#define NN 100000
#define EE 1600000
#define ELN 200000

#define NB 98           // dst buckets: dst >> 10, max 97
#define BKT_SHIFT 10
#define BKT_NODES 1024
#define MSB 256         // multisplit blocks
#define EPB (EE / MSB)  // 6250 edges per block

typedef __attribute__((ext_vector_type(4))) float f32x4;
typedef __attribute__((ext_vector_type(8))) short short8;

__device__ __forceinline__ unsigned short f2bf(float f) {
    unsigned u = __builtin_bit_cast(unsigned, f);
    u += 0x7FFF + ((u >> 16) & 1);   // round-to-nearest-even
    return (unsigned short)(u >> 16);
}
__device__ __forceinline__ float bf2f(unsigned short h) {
    return __builtin_bit_cast(float, (unsigned)h << 16);
}

// ----------------- weight pre-transpose: W[k][128] f32 -> WT[n][K] bf16 -----------------
__device__ __forceinline__ void convw_one(const float* __restrict__ W,
                                          unsigned short* __restrict__ WT, int K, int u) {
    int n = u & 127, kq = u >> 7;
    short8 t;
#pragma unroll
    for (int j = 0; j < 8; j++)
        t[j] = (short)f2bf(W[(size_t)(kq * 8 + j) * 128 + n]);
    *(short8*)(WT + (size_t)n * K + kq * 8) = t;
}

__global__ __launch_bounds__(256) void convw_kernel(const float* __restrict__ W1,
                                                    const float* __restrict__ W2,
                                                    const float* __restrict__ Wp1,
                                                    unsigned short* __restrict__ W1T,
                                                    unsigned short* __restrict__ W2T,
                                                    unsigned short* __restrict__ WpT) {
    int u = blockIdx.x * 256 + threadIdx.x;  // 8192 threads
    if (u < 2048) convw_one(W1, W1T, 128, u);
    else if (u < 4096) convw_one(W2, W2T, 128, u - 2048);
    else convw_one(Wp1, WpT, 256, u - 4096);
}

// ----------------- multisplit CSR build -----------------
__global__ __launch_bounds__(256) void ms_hist_kernel(const int* __restrict__ dst,
                                                      int* __restrict__ histM) {
    __shared__ int cnt[NB];
    int tid = threadIdx.x;
    if (tid < NB) cnt[tid] = 0;
    __syncthreads();
    int base = blockIdx.x * EPB;
    for (int i = tid; i < EPB; i += 256)
        atomicAdd(&cnt[dst[base + i] >> BKT_SHIFT], 1);
    __syncthreads();
    if (tid < NB) histM[tid * MSB + blockIdx.x] = cnt[tid];
}

// one-pass scan: 256 threads x 98 contiguous elements each (25088 total)
__global__ __launch_bounds__(256) void ms_scan_kernel(int* __restrict__ histM,
                                                      int* __restrict__ rowptr) {
    __shared__ int sm[256];
    int tid = threadIdx.x;
    const int CPT = NB * MSB / 256;  // 98
    int base = tid * CPT;
    int s = 0;
    for (int i = 0; i < CPT; i++) s += histM[base + i];
    sm[tid] = s;
    __syncthreads();
    for (int off = 1; off < 256; off <<= 1) {
        int add = (tid >= off) ? sm[tid - off] : 0;
        __syncthreads();
        sm[tid] += add;
        __syncthreads();
    }
    int run = sm[tid] - s;  // exclusive prefix of this thread's run
    for (int i = 0; i < CPT; i++) {
        int v = histM[base + i];
        histM[base + i] = run;
        run += v;
    }
    if (tid == 0) rowptr[NN] = EE;
}

__global__ __launch_bounds__(256) void ms_scatter_kernel(const int* __restrict__ src,
                                                         const int* __restrict__ dst,
                                                         const int* __restrict__ histO,
                                                         unsigned* __restrict__ tmp) {
    __shared__ int off[NB];
    int tid = threadIdx.x;
    if (tid < NB) off[tid] = histO[tid * MSB + blockIdx.x];
    __syncthreads();
    int base = blockIdx.x * EPB;
    for (int i = tid; i < EPB; i += 256) {
        int d = dst[base + i];
        int s = src[base + i];
        int b = d >> BKT_SHIFT;
        int pos = atomicAdd(&off[b], 1);
        tmp[pos] = ((unsigned)(d & (BKT_NODES - 1)) << 17) | (unsigned)s;
    }
}

// one block per bucket: build per-node counts, emit rowptr+dinv, scatter csr locally
__global__ __launch_bounds__(256) void bucket_csr_kernel(const unsigned* __restrict__ tmp,
                                                         const int* __restrict__ histO,
                                                         int* __restrict__ rowptr,
                                                         float* __restrict__ dinv,
                                                         int* __restrict__ csr) {
    __shared__ int cnt[BKT_NODES];
    __shared__ int lp[BKT_NODES];
    __shared__ int sm[256];
    int b = blockIdx.x;
    int tid = threadIdx.x;
    int gbase = histO[b * MSB];
    int gend = (b == NB - 1) ? EE : histO[(b + 1) * MSB];
    for (int i = tid; i < BKT_NODES; i += 256) cnt[i] = 0;
    __syncthreads();
    for (int i = gbase + tid; i < gend; i += 256)
        atomicAdd(&cnt[tmp[i] >> 17], 1);
    __syncthreads();
    // exclusive scan of cnt[1024] with 256 threads (4 elems each)
    int s0 = cnt[tid * 4], s1 = cnt[tid * 4 + 1], s2 = cnt[tid * 4 + 2], s3 = cnt[tid * 4 + 3];
    int tot = s0 + s1 + s2 + s3;
    sm[tid] = tot;
    __syncthreads();
    for (int off = 1; off < 256; off <<= 1) {
        int add = (tid >= off) ? sm[tid - off] : 0;
        __syncthreads();
        sm[tid] += add;
        __syncthreads();
    }
    int excl = sm[tid] - tot;
    lp[tid * 4] = excl;
    lp[tid * 4 + 1] = excl + s0;
    lp[tid * 4 + 2] = excl + s0 + s1;
    lp[tid * 4 + 3] = excl + s0 + s1 + s2;
    // emit rowptr + dinv, then reset cnt for position allocation
    int n0 = b << BKT_SHIFT;
#pragma unroll
    for (int q = 0; q < 4; q++) {
        int i = tid * 4 + q;
        int node = n0 + i;
        if (node < NN) {
            rowptr[node] = gbase + (q == 0 ? excl : lp[i]);
            int c = (q == 0) ? s0 : (q == 1 ? s1 : (q == 2 ? s2 : s3));
            dinv[node] = rsqrtf((float)c + 1.0f);
        }
    }
    cnt[tid * 4] = 0; cnt[tid * 4 + 1] = 0; cnt[tid * 4 + 2] = 0; cnt[tid * 4 + 3] = 0;
    __syncthreads();
    for (int i = gbase + tid; i < gend; i += 256) {
        unsigned p = tmp[i];
        int dl = p >> 17;
        int s = p & 0x1FFFF;
        int pos = atomicAdd(&cnt[dl], 1);
        csr[gbase + lp[dl] + pos] = s;
    }
}

// ----------------- GEMM via MFMA, epilogue pre-scales by dinv[row] ----------------------
// out: row-major bf16 [NN][128], g = dinv[row] * (A@W)[row];  A = f32 row-major [NN][128]
__global__ __launch_bounds__(256) void gemm_mfma_kernel(const float* __restrict__ Av,
                                                        const unsigned short* __restrict__ WT,
                                                        const float* __restrict__ dinv,
                                                        unsigned short* __restrict__ out,
                                                        int nchunks) {
    __shared__ __align__(16) char Wl[128 * 128 * 2];  // 32 KB: WT[n][k] bf16, swizzled
    int tid = threadIdx.x;
#pragma unroll
    for (int j = 0; j < 8; j++) {
        int slot = tid + j * 256;           // 2048 slots of 16B
        int n = slot >> 4, k0 = (slot & 15) * 8;
        int byte = (n * 256 + k0 * 2) ^ ((n & 7) << 4);
        *(short8*)(Wl + byte) = ((const short8*)WT)[slot];
    }
    __syncthreads();
    int wid = tid >> 6, l = tid & 63;
    int lhi = l >> 4, llo = l & 15;
    for (int chunk = blockIdx.x; chunk < nchunks; chunk += gridDim.x) {
        int r0 = chunk * 64 + wid * 16;
        int arow = r0 + llo;
        f32x4 acc[8];
#pragma unroll
        for (int c = 0; c < 8; c++) acc[c] = (f32x4)0.0f;
#pragma unroll
        for (int ks = 0; ks < 4; ks++) {
            int koff = ks * 32 + lhi * 8;
            short8 a;
            if (arow < NN) {
                const float* ap = Av + (size_t)arow * 128 + koff;
                float4 v0 = *(const float4*)ap;
                float4 v1 = *(const float4*)(ap + 4);
                a[0] = (short)f2bf(v0.x); a[1] = (short)f2bf(v0.y);
                a[2] = (short)f2bf(v0.z); a[3] = (short)f2bf(v0.w);
                a[4] = (short)f2bf(v1.x); a[5] = (short)f2bf(v1.y);
                a[6] = (short)f2bf(v1.z); a[7] = (short)f2bf(v1.w);
            } else {
                a = (short8)(short)0;
            }
#pragma unroll
            for (int c = 0; c < 8; c++) {
                int n = c * 16 + llo;
                int byte = (n * 256 + koff * 2) ^ ((n & 7) << 4);
                short8 bfr = *(const short8*)(Wl + byte);
                acc[c] = __builtin_amdgcn_mfma_f32_16x16x32_bf16(a, bfr, acc[c], 0, 0, 0);
            }
        }
        float dv[4];
#pragma unroll
        for (int j = 0; j < 4; j++) {
            int row = r0 + lhi * 4 + j;
            dv[j] = (row < NN) ? dinv[row] : 0.f;
        }
#pragma unroll
        for (int c = 0; c < 8; c++) {
            int col = c * 16 + llo;
#pragma unroll
            for (int j = 0; j < 4; j++) {
                int row = r0 + lhi * 4 + j;
                if (row < NN)
                    out[(size_t)row * 128 + col] = f2bf(acc[c][j] * dv[j]);
            }
        }
    }
}

// ----------------- fused agg1 + gemm2 -----------------
// Gather: 16-lane groups, lane(t=l>>4, q=l&15): group t gathers rows as short8 (16B/lane,
// 4 rows per wave-instruction). Per wave: 16 nodes (tb=0..3), h1=relu(dn*sum+b1) stashed
// bf16 in wave-private LDS tile (XOR-swizzled), then MFMA -> g2=dinv*(h1@W2).
// W2T B-fragments read DIRECTLY from global (32KB, L2/L1-resident) -- no Wl staging,
// LDS halves to 32KB so occupancy doubles (gather latency coverage).
__global__ __launch_bounds__(512) void agg1_gemm2_kernel(const unsigned short* __restrict__ g1,
                                                         const unsigned short* __restrict__ W2T,
                                                         const int* __restrict__ rowptr,
                                                         const int* __restrict__ csr,
                                                         const float* __restrict__ dinv,
                                                         const float* __restrict__ b1,
                                                         unsigned short* __restrict__ g2) {
    __shared__ __align__(16) char Ht[8][16 * 128 * 2]; // 4 KB/wave h1 tile, swizzled
    int tid = threadIdx.x;
    int w = tid >> 6, l = tid & 63;
    int t = l >> 4, q = l & 15;
    char* ht = Ht[w];
    int base = blockIdx.x * 128 + w * 16;   // wave's 16 nodes
    float bb[8];
#pragma unroll
    for (int j = 0; j < 8; j++) bb[j] = b1[q * 8 + j];
#pragma unroll
    for (int tb = 0; tb < 4; tb++) {
        int node = base + tb * 4 + t;
        float a[8];
#pragma unroll
        for (int j = 0; j < 8; j++) a[j] = 0.f;
        if (node < NN) {
            short8 sv = *(const short8*)(g1 + (size_t)node * 128 + q * 8);
#pragma unroll
            for (int j = 0; j < 8; j++) a[j] += bf2f((unsigned short)sv[j]);
            int beg = rowptr[node], end = rowptr[node + 1];
            int i = beg;
            for (; i + 4 <= end; i += 4) {
                int s0 = csr[i], s1 = csr[i + 1], s2 = csr[i + 2], s3 = csr[i + 3];
                short8 v0 = *(const short8*)(g1 + (size_t)s0 * 128 + q * 8);
                short8 v1 = *(const short8*)(g1 + (size_t)s1 * 128 + q * 8);
                short8 v2 = *(const short8*)(g1 + (size_t)s2 * 128 + q * 8);
                short8 v3 = *(const short8*)(g1 + (size_t)s3 * 128 + q * 8);
#pragma unroll
                for (int j = 0; j < 8; j++) {
                    a[j] += bf2f((unsigned short)v0[j]);
                    a[j] += bf2f((unsigned short)v1[j]);
                    a[j] += bf2f((unsigned short)v2[j]);
                    a[j] += bf2f((unsigned short)v3[j]);
                }
            }
            for (; i < end; i++) {
                int s = csr[i];
                short8 v = *(const short8*)(g1 + (size_t)s * 128 + q * 8);
#pragma unroll
                for (int j = 0; j < 8; j++) a[j] += bf2f((unsigned short)v[j]);
            }
            float dn = dinv[node];
#pragma unroll
            for (int j = 0; j < 8; j++) a[j] = fmaxf(fmaf(dn, a[j], bb[j]), 0.f);
        }
        short8 hr;
#pragma unroll
        for (int j = 0; j < 8; j++) hr[j] = (short)f2bf(a[j]);
        int r = tb * 4 + t;
        int byte = (r * 256 + q * 16) ^ ((r & 7) << 4);
        *(short8*)(ht + byte) = hr;
    }
    // MFMA phase: wave-private tile (compiler inserts lgkmcnt wait); B direct from global
    int llo = q, lhi = t;
    f32x4 acc[8];
#pragma unroll
    for (int c = 0; c < 8; c++) acc[c] = (f32x4)0.0f;
#pragma unroll
    for (int ks = 0; ks < 4; ks++) {
        int koff = ks * 32 + lhi * 8;
        int abyte = (llo * 256 + koff * 2) ^ ((llo & 7) << 4);
        short8 afr = *(const short8*)(ht + abyte);
#pragma unroll
        for (int c = 0; c < 8; c++) {
            int n = c * 16 + llo;
            short8 bfr = *(const short8*)(W2T + (size_t)n * 128 + koff);
            acc[c] = __builtin_amdgcn_mfma_f32_16x16x32_bf16(afr, bfr, acc[c], 0, 0, 0);
        }
    }
    float dv[4];
#pragma unroll
    for (int j = 0; j < 4; j++) {
        int row = base + lhi * 4 + j;
        dv[j] = (row < NN) ? dinv[row] : 0.f;
    }
#pragma unroll
    for (int c = 0; c < 8; c++) {
        int col = c * 16 + llo;
#pragma unroll
        for (int j = 0; j < 4; j++) {
            int row = base + lhi * 4 + j;
            if (row < NN)
                g2[(size_t)row * 128 + col] = f2bf(acc[c][j] * dv[j]);
        }
    }
}

// ----------------- agg layer 2: 16-lane-group gather, direct row store -----------------
__global__ __launch_bounds__(512) void agg2_kernel(const unsigned short* __restrict__ g,
                                                   const int* __restrict__ rowptr,
                                                   const int* __restrict__ csr,
                                                   const float* __restrict__ dinv,
                                                   const float* __restrict__ bias,
                                                   unsigned short* __restrict__ out) {
    int w = threadIdx.x >> 6, l = threadIdx.x & 63;
    int t = l >> 4, q = l & 15;
    int node = blockIdx.x * 32 + w * 4 + t;
    if (node >= NN) return;
    float a[8];
    short8 sv = *(const short8*)(g + (size_t)node * 128 + q * 8);
#pragma unroll
    for (int j = 0; j < 8; j++) a[j] = bf2f((unsigned short)sv[j]);
    int beg = rowptr[node], end = rowptr[node + 1];
    int i = beg;
    for (; i + 4 <= end; i += 4) {
        int s0 = csr[i], s1 = csr[i + 1], s2 = csr[i + 2], s3 = csr[i + 3];
        short8 v0 = *(const short8*)(g + (size_t)s0 * 128 + q * 8);
        short8 v1 = *(const short8*)(g + (size_t)s1 * 128 + q * 8);
        short8 v2 = *(const short8*)(g + (size_t)s2 * 128 + q * 8);
        short8 v3 = *(const short8*)(g + (size_t)s3 * 128 + q * 8);
#pragma unroll
        for (int j = 0; j < 8; j++) {
            a[j] += bf2f((unsigned short)v0[j]);
            a[j] += bf2f((unsigned short)v1[j]);
            a[j] += bf2f((unsigned short)v2[j]);
            a[j] += bf2f((unsigned short)v3[j]);
        }
    }
    for (; i < end; i++) {
        int s = csr[i];
        short8 v = *(const short8*)(g + (size_t)s * 128 + q * 8);
#pragma unroll
        for (int j = 0; j < 8; j++) a[j] += bf2f((unsigned short)v[j]);
    }
    float dn = dinv[node];
    short8 hr;
#pragma unroll
    for (int j = 0; j < 8; j++) hr[j] = (short)f2bf(fmaf(dn, a[j], bias[q * 8 + j]));
    *(short8*)(out + (size_t)node * 128 + q * 8) = hr;
}

// ----------------- link scoring via MFMA -----------------
// 8 waves x 16 edges per block-iter; WpT pre-transposed bf16, vector-staged to LDS.
__global__ __launch_bounds__(512, 2) void link_mfma_kernel(const unsigned short* __restrict__ h,
                                                           const int* __restrict__ eli,
                                                           const unsigned short* __restrict__ WpT,
                                                           const float* __restrict__ bp1,
                                                           const float* __restrict__ Wp2,
                                                           const float* __restrict__ bp2,
                                                           float* __restrict__ out) {
    __shared__ __align__(16) char Wl[128 * 256 * 2];  // 64 KB: WpT[n][k] bf16, swizzled
    int tid = threadIdx.x;
#pragma unroll
    for (int j = 0; j < 8; j++) {
        int slot = tid + j * 512;           // 4096 slots of 16B
        int n = slot >> 5, k0 = (slot & 31) * 8;
        int byte = (n * 512 + k0 * 2) ^ ((n & 7) << 4);
        *(short8*)(Wl + byte) = ((const short8*)WpT)[slot];
    }
    __syncthreads();
    int wid = tid >> 6, l = tid & 63;
    int lhi = l >> 4, llo = l & 15;
    float b2 = bp2[0];
    const int NG = (ELN + 127) / 128;  // 1563, last group partial
    for (int g = blockIdx.x; g < NG; g += gridDim.x) {
        int e_base = g * 128 + wid * 16;
        if (e_base >= ELN) continue;
        int ea = e_base + llo;
        int es = eli[ea], et = eli[ELN + ea];
        f32x4 acc[8];
#pragma unroll
        for (int c = 0; c < 8; c++) acc[c] = (f32x4)0.0f;
#pragma unroll
        for (int ks = 0; ks < 8; ks++) {
            int kg = ks * 32 + lhi * 8;          // emb k in [0,256)
            int row = (kg < 128) ? es : et;
            int koff = kg & 127;
            short8 a = *(const short8*)(h + (size_t)row * 128 + koff);
#pragma unroll
            for (int c = 0; c < 8; c++) {
                int n = c * 16 + llo;
                int byte = (n * 512 + kg * 2) ^ ((n & 7) << 4);
                short8 bfr = *(const short8*)(Wl + byte);
                acc[c] = __builtin_amdgcn_mfma_f32_16x16x32_bf16(a, bfr, acc[c], 0, 0, 0);
            }
        }
        float p0 = 0.f, p1 = 0.f, p2 = 0.f, p3 = 0.f;
#pragma unroll
        for (int c = 0; c < 8; c++) {
            int col = c * 16 + llo;
            float bb = bp1[col];
            float w2 = Wp2[col];
            p0 += fmaxf(acc[c][0] + bb, 0.f) * w2;
            p1 += fmaxf(acc[c][1] + bb, 0.f) * w2;
            p2 += fmaxf(acc[c][2] + bb, 0.f) * w2;
            p3 += fmaxf(acc[c][3] + bb, 0.f) * w2;
        }
#pragma unroll
        for (int off = 1; off < 16; off <<= 1) {
            p0 += __shfl_xor(p0, off);
            p1 += __shfl_xor(p1, off);
            p2 += __shfl_xor(p2, off);
            p3 += __shfl_xor(p3, off);
        }
        if (llo == 0) {
            int e = e_base + lhi * 4;
            out[e + 0] = p0 + b2;
            out[e + 1] = p1 + b2;
            out[e + 2] = p2 + b2;
            out[e + 3] = p3 + b2;
        }
    }
}

extern "C" void kernel_launch(void* const* d_in, const int* in_sizes, int n_in,
                              void* d_out, int out_size, void* d_ws, size_t ws_size,
                              hipStream_t stream) {
    const float* x   = (const float*)d_in[0];
    const int*   ei  = (const int*)d_in[1];
    const int*   eli = (const int*)d_in[2];
    const float* W1  = (const float*)d_in[3];
    const float* b1  = (const float*)d_in[4];
    const float* W2  = (const float*)d_in[5];
    const float* b2  = (const float*)d_in[6];
    const float* Wp1 = (const float*)d_in[7];
    const float* bp1 = (const float*)d_in[8];
    const float* Wp2 = (const float*)d_in[9];
    const float* bp2 = (const float*)d_in[10];
    float* out = (float*)d_out;

    char* w = (char*)d_ws;
    auto alloc = [&](size_t bytes) {
        char* p = w;
        w += (bytes + 255) & ~(size_t)255;
        return p;
    };
    float*          dinv   = (float*)alloc((size_t)NN * 4);
    int*            rowptr = (int*)alloc((size_t)(NN + 1) * 4);
    int*            histM  = (int*)alloc((size_t)NB * MSB * 4);
    unsigned*       tmp    = (unsigned*)alloc((size_t)EE * 4);
    int*            csr    = (int*)alloc((size_t)EE * 4);
    unsigned short* gbuf   = (unsigned short*)alloc((size_t)NN * 128 * 2);  // g1 then h2
    unsigned short* hbuf   = (unsigned short*)alloc((size_t)NN * 128 * 2);  // g2
    unsigned short* W1T    = (unsigned short*)alloc((size_t)128 * 128 * 2);
    unsigned short* W2T    = (unsigned short*)alloc((size_t)128 * 128 * 2);
    unsigned short* WpT    = (unsigned short*)alloc((size_t)128 * 256 * 2);

    const int* srcv = ei;       // row 0
    const int* dstv = ei + EE;  // row 1

    // weight pre-transpose (bf16 [n][k])
    convw_kernel<<<32, 256, 0, stream>>>(W1, W2, Wp1, W1T, W2T, WpT);

    // CSR build: multisplit by dst bucket, then per-bucket local CSR (+rowptr,+dinv)
    ms_hist_kernel<<<MSB, 256, 0, stream>>>(dstv, histM);
    ms_scan_kernel<<<1, 256, 0, stream>>>(histM, rowptr);
    ms_scatter_kernel<<<MSB, 256, 0, stream>>>(srcv, dstv, histM, tmp);
    bucket_csr_kernel<<<NB, 256, 0, stream>>>(tmp, histM, rowptr, dinv, csr);

    int nchunks = (NN + 63) / 64;  // 1563
    // g1 = dinv*(x@W1)
    gemm_mfma_kernel<<<1024, 256, 0, stream>>>(x, W1T, dinv, gbuf, nchunks);
    // fused: h1 = relu(dn*sum(g1)+b1); g2 = dinv*(h1@W2)
    agg1_gemm2_kernel<<<(NN + 127) / 128, 512, 0, stream>>>(gbuf, W2T, rowptr, csr, dinv, b1, hbuf);
    // h2 = dn*sum(g2)+b2 (row-major)
    agg2_kernel<<<(NN + 31) / 32, 512, 0, stream>>>(hbuf, rowptr, csr, dinv, b2, gbuf);
    // link scoring (reads row-major h2)
    link_mfma_kernel<<<512, 512, 0, stream>>>(gbuf, eli, WpT, bp1, Wp2, bp2, out);
}

// Round 15
// 278.506 us; speedup vs baseline: 1.0885x; 1.0885x over previous
//
#include <hip/hip_runtime.h>

#define NN 100000
#define EE 1600000
#define ELN 200000

#define NB 98           // dst buckets: dst >> 10, max 97
#define BKT_SHIFT 10
#define BKT_NODES 1024
#define MSB 256         // multisplit blocks
#define EPB (EE / MSB)  // 6250 edges per block

typedef __attribute__((ext_vector_type(4))) float f32x4;
typedef __attribute__((ext_vector_type(8))) short short8;

__device__ __forceinline__ unsigned short f2bf(float f) {
    unsigned u = __builtin_bit_cast(unsigned, f);
    u += 0x7FFF + ((u >> 16) & 1);   // round-to-nearest-even
    return (unsigned short)(u >> 16);
}
__device__ __forceinline__ float bf2f(unsigned short h) {
    return __builtin_bit_cast(float, (unsigned)h << 16);
}

// ----------------- weight pre-transpose: W[k][128] f32 -> WT[n][K] bf16 -----------------
__device__ __forceinline__ void convw_one(const float* __restrict__ W,
                                          unsigned short* __restrict__ WT, int K, int u) {
    int n = u & 127, kq = u >> 7;
    short8 t;
#pragma unroll
    for (int j = 0; j < 8; j++)
        t[j] = (short)f2bf(W[(size_t)(kq * 8 + j) * 128 + n]);
    *(short8*)(WT + (size_t)n * K + kq * 8) = t;
}

__global__ __launch_bounds__(256) void convw_kernel(const float* __restrict__ W1,
                                                    const float* __restrict__ W2,
                                                    const float* __restrict__ Wp1,
                                                    unsigned short* __restrict__ W1T,
                                                    unsigned short* __restrict__ W2T,
                                                    unsigned short* __restrict__ WpT) {
    int u = blockIdx.x * 256 + threadIdx.x;  // 8192 threads
    if (u < 2048) convw_one(W1, W1T, 128, u);
    else if (u < 4096) convw_one(W2, W2T, 128, u - 2048);
    else convw_one(Wp1, WpT, 256, u - 4096);
}

// ----------------- multisplit CSR build -----------------
__global__ __launch_bounds__(256) void ms_hist_kernel(const int* __restrict__ dst,
                                                      int* __restrict__ histM) {
    __shared__ int cnt[NB];
    int tid = threadIdx.x;
    if (tid < NB) cnt[tid] = 0;
    __syncthreads();
    int base = blockIdx.x * EPB;
    for (int i = tid; i < EPB; i += 256)
        atomicAdd(&cnt[dst[base + i] >> BKT_SHIFT], 1);
    __syncthreads();
    if (tid < NB) histM[tid * MSB + blockIdx.x] = cnt[tid];
}

// one-pass scan: 256 threads x 98 contiguous elements each (25088 total)
__global__ __launch_bounds__(256) void ms_scan_kernel(int* __restrict__ histM,
                                                      int* __restrict__ rowptr) {
    __shared__ int sm[256];
    int tid = threadIdx.x;
    const int CPT = NB * MSB / 256;  // 98
    int base = tid * CPT;
    int s = 0;
    for (int i = 0; i < CPT; i++) s += histM[base + i];
    sm[tid] = s;
    __syncthreads();
    for (int off = 1; off < 256; off <<= 1) {
        int add = (tid >= off) ? sm[tid - off] : 0;
        __syncthreads();
        sm[tid] += add;
        __syncthreads();
    }
    int run = sm[tid] - s;  // exclusive prefix of this thread's run
    for (int i = 0; i < CPT; i++) {
        int v = histM[base + i];
        histM[base + i] = run;
        run += v;
    }
    if (tid == 0) rowptr[NN] = EE;
}

__global__ __launch_bounds__(256) void ms_scatter_kernel(const int* __restrict__ src,
                                                         const int* __restrict__ dst,
                                                         const int* __restrict__ histO,
                                                         unsigned* __restrict__ tmp) {
    __shared__ int off[NB];
    int tid = threadIdx.x;
    if (tid < NB) off[tid] = histO[tid * MSB + blockIdx.x];
    __syncthreads();
    int base = blockIdx.x * EPB;
    for (int i = tid; i < EPB; i += 256) {
        int d = dst[base + i];
        int s = src[base + i];
        int b = d >> BKT_SHIFT;
        int pos = atomicAdd(&off[b], 1);
        tmp[pos] = ((unsigned)(d & (BKT_NODES - 1)) << 17) | (unsigned)s;
    }
}

// one block per bucket: build per-node counts, emit rowptr+dinv, scatter csr locally
__global__ __launch_bounds__(256) void bucket_csr_kernel(const unsigned* __restrict__ tmp,
                                                         const int* __restrict__ histO,
                                                         int* __restrict__ rowptr,
                                                         float* __restrict__ dinv,
                                                         int* __restrict__ csr) {
    __shared__ int cnt[BKT_NODES];
    __shared__ int lp[BKT_NODES];
    __shared__ int sm[256];
    int b = blockIdx.x;
    int tid = threadIdx.x;
    int gbase = histO[b * MSB];
    int gend = (b == NB - 1) ? EE : histO[(b + 1) * MSB];
    for (int i = tid; i < BKT_NODES; i += 256) cnt[i] = 0;
    __syncthreads();
    for (int i = gbase + tid; i < gend; i += 256)
        atomicAdd(&cnt[tmp[i] >> 17], 1);
    __syncthreads();
    // exclusive scan of cnt[1024] with 256 threads (4 elems each)
    int s0 = cnt[tid * 4], s1 = cnt[tid * 4 + 1], s2 = cnt[tid * 4 + 2], s3 = cnt[tid * 4 + 3];
    int tot = s0 + s1 + s2 + s3;
    sm[tid] = tot;
    __syncthreads();
    for (int off = 1; off < 256; off <<= 1) {
        int add = (tid >= off) ? sm[tid - off] : 0;
        __syncthreads();
        sm[tid] += add;
        __syncthreads();
    }
    int excl = sm[tid] - tot;
    lp[tid * 4] = excl;
    lp[tid * 4 + 1] = excl + s0;
    lp[tid * 4 + 2] = excl + s0 + s1;
    lp[tid * 4 + 3] = excl + s0 + s1 + s2;
    // emit rowptr + dinv, then reset cnt for position allocation
    int n0 = b << BKT_SHIFT;
#pragma unroll
    for (int q = 0; q < 4; q++) {
        int i = tid * 4 + q;
        int node = n0 + i;
        if (node < NN) {
            rowptr[node] = gbase + (q == 0 ? excl : lp[i]);
            int c = (q == 0) ? s0 : (q == 1 ? s1 : (q == 2 ? s2 : s3));
            dinv[node] = rsqrtf((float)c + 1.0f);
        }
    }
    cnt[tid * 4] = 0; cnt[tid * 4 + 1] = 0; cnt[tid * 4 + 2] = 0; cnt[tid * 4 + 3] = 0;
    __syncthreads();
    for (int i = gbase + tid; i < gend; i += 256) {
        unsigned p = tmp[i];
        int dl = p >> 17;
        int s = p & 0x1FFFF;
        int pos = atomicAdd(&cnt[dl], 1);
        csr[gbase + lp[dl] + pos] = s;
    }
}

// ----------------- GEMM via MFMA, epilogue pre-scales by dinv[row] ----------------------
// out: row-major bf16 [NN][128], g = dinv[row] * (A@W)[row];  A = f32 row-major [NN][128]
__global__ __launch_bounds__(256) void gemm_mfma_kernel(const float* __restrict__ Av,
                                                        const unsigned short* __restrict__ WT,
                                                        const float* __restrict__ dinv,
                                                        unsigned short* __restrict__ out,
                                                        int nchunks) {
    __shared__ __align__(16) char Wl[128 * 128 * 2];  // 32 KB: WT[n][k] bf16, swizzled
    int tid = threadIdx.x;
#pragma unroll
    for (int j = 0; j < 8; j++) {
        int slot = tid + j * 256;           // 2048 slots of 16B
        int n = slot >> 4, k0 = (slot & 15) * 8;
        int byte = (n * 256 + k0 * 2) ^ ((n & 7) << 4);
        *(short8*)(Wl + byte) = ((const short8*)WT)[slot];
    }
    __syncthreads();
    int wid = tid >> 6, l = tid & 63;
    int lhi = l >> 4, llo = l & 15;
    for (int chunk = blockIdx.x; chunk < nchunks; chunk += gridDim.x) {
        int r0 = chunk * 64 + wid * 16;
        int arow = r0 + llo;
        f32x4 acc[8];
#pragma unroll
        for (int c = 0; c < 8; c++) acc[c] = (f32x4)0.0f;
#pragma unroll
        for (int ks = 0; ks < 4; ks++) {
            int koff = ks * 32 + lhi * 8;
            short8 a;
            if (arow < NN) {
                const float* ap = Av + (size_t)arow * 128 + koff;
                float4 v0 = *(const float4*)ap;
                float4 v1 = *(const float4*)(ap + 4);
                a[0] = (short)f2bf(v0.x); a[1] = (short)f2bf(v0.y);
                a[2] = (short)f2bf(v0.z); a[3] = (short)f2bf(v0.w);
                a[4] = (short)f2bf(v1.x); a[5] = (short)f2bf(v1.y);
                a[6] = (short)f2bf(v1.z); a[7] = (short)f2bf(v1.w);
            } else {
                a = (short8)(short)0;
            }
#pragma unroll
            for (int c = 0; c < 8; c++) {
                int n = c * 16 + llo;
                int byte = (n * 256 + koff * 2) ^ ((n & 7) << 4);
                short8 bfr = *(const short8*)(Wl + byte);
                acc[c] = __builtin_amdgcn_mfma_f32_16x16x32_bf16(a, bfr, acc[c], 0, 0, 0);
            }
        }
        float dv[4];
#pragma unroll
        for (int j = 0; j < 4; j++) {
            int row = r0 + lhi * 4 + j;
            dv[j] = (row < NN) ? dinv[row] : 0.f;
        }
#pragma unroll
        for (int c = 0; c < 8; c++) {
            int col = c * 16 + llo;
#pragma unroll
            for (int j = 0; j < 4; j++) {
                int row = r0 + lhi * 4 + j;
                if (row < NN)
                    out[(size_t)row * 128 + col] = f2bf(acc[c][j] * dv[j]);
            }
        }
    }
}

// ----------------- fused agg1 + gemm2 -----------------
// Gather: 16-lane groups, lane(t=l>>4, q=l&15): group t gathers rows as short8 (16B/lane,
// 4 rows per wave-instruction). Per wave: 16 nodes (tb=0..3), h1=relu(dn*sum+b1) stashed
// bf16 in wave-private LDS tile (XOR-swizzled), then MFMA vs LDS W2T -> g2=dinv*(h1@W2).
__global__ __launch_bounds__(512) void agg1_gemm2_kernel(const unsigned short* __restrict__ g1,
                                                         const unsigned short* __restrict__ W2T,
                                                         const int* __restrict__ rowptr,
                                                         const int* __restrict__ csr,
                                                         const float* __restrict__ dinv,
                                                         const float* __restrict__ b1,
                                                         unsigned short* __restrict__ g2) {
    __shared__ __align__(16) char Wl[128 * 128 * 2];   // 32 KB swizzled W2T[n][k]
    __shared__ __align__(16) char Ht[8][16 * 128 * 2]; // 4 KB/wave h1 tile, swizzled
    int tid = threadIdx.x;
#pragma unroll
    for (int j = 0; j < 4; j++) {
        int slot = tid + j * 512;           // 2048 slots of 16B
        int n = slot >> 4, k0 = (slot & 15) * 8;
        int byte = (n * 256 + k0 * 2) ^ ((n & 7) << 4);
        *(short8*)(Wl + byte) = ((const short8*)W2T)[slot];
    }
    __syncthreads();
    int w = tid >> 6, l = tid & 63;
    int t = l >> 4, q = l & 15;
    char* ht = Ht[w];
    int base = blockIdx.x * 128 + w * 16;   // wave's 16 nodes
    float bb[8];
#pragma unroll
    for (int j = 0; j < 8; j++) bb[j] = b1[q * 8 + j];
#pragma unroll
    for (int tb = 0; tb < 4; tb++) {
        int node = base + tb * 4 + t;
        float a[8];
#pragma unroll
        for (int j = 0; j < 8; j++) a[j] = 0.f;
        if (node < NN) {
            short8 sv = *(const short8*)(g1 + (size_t)node * 128 + q * 8);
#pragma unroll
            for (int j = 0; j < 8; j++) a[j] += bf2f((unsigned short)sv[j]);
            int beg = rowptr[node], end = rowptr[node + 1];
            int i = beg;
            for (; i + 4 <= end; i += 4) {
                int s0 = csr[i], s1 = csr[i + 1], s2 = csr[i + 2], s3 = csr[i + 3];
                short8 v0 = *(const short8*)(g1 + (size_t)s0 * 128 + q * 8);
                short8 v1 = *(const short8*)(g1 + (size_t)s1 * 128 + q * 8);
                short8 v2 = *(const short8*)(g1 + (size_t)s2 * 128 + q * 8);
                short8 v3 = *(const short8*)(g1 + (size_t)s3 * 128 + q * 8);
#pragma unroll
                for (int j = 0; j < 8; j++) {
                    a[j] += bf2f((unsigned short)v0[j]);
                    a[j] += bf2f((unsigned short)v1[j]);
                    a[j] += bf2f((unsigned short)v2[j]);
                    a[j] += bf2f((unsigned short)v3[j]);
                }
            }
            for (; i < end; i++) {
                int s = csr[i];
                short8 v = *(const short8*)(g1 + (size_t)s * 128 + q * 8);
#pragma unroll
                for (int j = 0; j < 8; j++) a[j] += bf2f((unsigned short)v[j]);
            }
            float dn = dinv[node];
#pragma unroll
            for (int j = 0; j < 8; j++) a[j] = fmaxf(fmaf(dn, a[j], bb[j]), 0.f);
        }
        short8 hr;
#pragma unroll
        for (int j = 0; j < 8; j++) hr[j] = (short)f2bf(a[j]);
        int r = tb * 4 + t;
        int byte = (r * 256 + q * 16) ^ ((r & 7) << 4);
        *(short8*)(ht + byte) = hr;
    }
    // MFMA phase: wave-private tile, no barrier needed (compiler inserts lgkmcnt wait)
    int llo = q, lhi = t;
    f32x4 acc[8];
#pragma unroll
    for (int c = 0; c < 8; c++) acc[c] = (f32x4)0.0f;
#pragma unroll
    for (int ks = 0; ks < 4; ks++) {
        int koff = ks * 32 + lhi * 8;
        int abyte = (llo * 256 + koff * 2) ^ ((llo & 7) << 4);
        short8 afr = *(const short8*)(ht + abyte);
#pragma unroll
        for (int c = 0; c < 8; c++) {
            int n = c * 16 + llo;
            int byte = (n * 256 + koff * 2) ^ ((n & 7) << 4);
            short8 bfr = *(const short8*)(Wl + byte);
            acc[c] = __builtin_amdgcn_mfma_f32_16x16x32_bf16(afr, bfr, acc[c], 0, 0, 0);
        }
    }
    float dv[4];
#pragma unroll
    for (int j = 0; j < 4; j++) {
        int row = base + lhi * 4 + j;
        dv[j] = (row < NN) ? dinv[row] : 0.f;
    }
#pragma unroll
    for (int c = 0; c < 8; c++) {
        int col = c * 16 + llo;
#pragma unroll
        for (int j = 0; j < 4; j++) {
            int row = base + lhi * 4 + j;
            if (row < NN)
                g2[(size_t)row * 128 + col] = f2bf(acc[c][j] * dv[j]);
        }
    }
}

// ----------------- agg layer 2: 16-lane-group gather, direct row store -----------------
__global__ __launch_bounds__(512) void agg2_kernel(const unsigned short* __restrict__ g,
                                                   const int* __restrict__ rowptr,
                                                   const int* __restrict__ csr,
                                                   const float* __restrict__ dinv,
                                                   const float* __restrict__ bias,
                                                   unsigned short* __restrict__ out) {
    int w = threadIdx.x >> 6, l = threadIdx.x & 63;
    int t = l >> 4, q = l & 15;
    int node = blockIdx.x * 32 + w * 4 + t;
    if (node >= NN) return;
    float a[8];
    short8 sv = *(const short8*)(g + (size_t)node * 128 + q * 8);
#pragma unroll
    for (int j = 0; j < 8; j++) a[j] = bf2f((unsigned short)sv[j]);
    int beg = rowptr[node], end = rowptr[node + 1];
    int i = beg;
    for (; i + 4 <= end; i += 4) {
        int s0 = csr[i], s1 = csr[i + 1], s2 = csr[i + 2], s3 = csr[i + 3];
        short8 v0 = *(const short8*)(g + (size_t)s0 * 128 + q * 8);
        short8 v1 = *(const short8*)(g + (size_t)s1 * 128 + q * 8);
        short8 v2 = *(const short8*)(g + (size_t)s2 * 128 + q * 8);
        short8 v3 = *(const short8*)(g + (size_t)s3 * 128 + q * 8);
#pragma unroll
        for (int j = 0; j < 8; j++) {
            a[j] += bf2f((unsigned short)v0[j]);
            a[j] += bf2f((unsigned short)v1[j]);
            a[j] += bf2f((unsigned short)v2[j]);
            a[j] += bf2f((unsigned short)v3[j]);
        }
    }
    for (; i < end; i++) {
        int s = csr[i];
        short8 v = *(const short8*)(g + (size_t)s * 128 + q * 8);
#pragma unroll
        for (int j = 0; j < 8; j++) a[j] += bf2f((unsigned short)v[j]);
    }
    float dn = dinv[node];
    short8 hr;
#pragma unroll
    for (int j = 0; j < 8; j++) hr[j] = (short)f2bf(fmaf(dn, a[j], bias[q * 8 + j]));
    *(short8*)(out + (size_t)node * 128 + q * 8) = hr;
}

// ----------------- link scoring via MFMA -----------------
// 8 waves x 16 edges per block-iter; WpT pre-transposed bf16, vector-staged to LDS.
__global__ __launch_bounds__(512, 2) void link_mfma_kernel(const unsigned short* __restrict__ h,
                                                           const int* __restrict__ eli,
                                                           const unsigned short* __restrict__ WpT,
                                                           const float* __restrict__ bp1,
                                                           const float* __restrict__ Wp2,
                                                           const float* __restrict__ bp2,
                                                           float* __restrict__ out) {
    __shared__ __align__(16) char Wl[128 * 256 * 2];  // 64 KB: WpT[n][k] bf16, swizzled
    int tid = threadIdx.x;
#pragma unroll
    for (int j = 0; j < 8; j++) {
        int slot = tid + j * 512;           // 4096 slots of 16B
        int n = slot >> 5, k0 = (slot & 31) * 8;
        int byte = (n * 512 + k0 * 2) ^ ((n & 7) << 4);
        *(short8*)(Wl + byte) = ((const short8*)WpT)[slot];
    }
    __syncthreads();
    int wid = tid >> 6, l = tid & 63;
    int lhi = l >> 4, llo = l & 15;
    float b2 = bp2[0];
    const int NG = (ELN + 127) / 128;  // 1563, last group partial
    for (int g = blockIdx.x; g < NG; g += gridDim.x) {
        int e_base = g * 128 + wid * 16;
        if (e_base >= ELN) continue;
        int ea = e_base + llo;
        int es = eli[ea], et = eli[ELN + ea];
        f32x4 acc[8];
#pragma unroll
        for (int c = 0; c < 8; c++) acc[c] = (f32x4)0.0f;
#pragma unroll
        for (int ks = 0; ks < 8; ks++) {
            int kg = ks * 32 + lhi * 8;          // emb k in [0,256)
            int row = (kg < 128) ? es : et;
            int koff = kg & 127;
            short8 a = *(const short8*)(h + (size_t)row * 128 + koff);
#pragma unroll
            for (int c = 0; c < 8; c++) {
                int n = c * 16 + llo;
                int byte = (n * 512 + kg * 2) ^ ((n & 7) << 4);
                short8 bfr = *(const short8*)(Wl + byte);
                acc[c] = __builtin_amdgcn_mfma_f32_16x16x32_bf16(a, bfr, acc[c], 0, 0, 0);
            }
        }
        float p0 = 0.f, p1 = 0.f, p2 = 0.f, p3 = 0.f;
#pragma unroll
        for (int c = 0; c < 8; c++) {
            int col = c * 16 + llo;
            float bb = bp1[col];
            float w2 = Wp2[col];
            p0 += fmaxf(acc[c][0] + bb, 0.f) * w2;
            p1 += fmaxf(acc[c][1] + bb, 0.f) * w2;
            p2 += fmaxf(acc[c][2] + bb, 0.f) * w2;
            p3 += fmaxf(acc[c][3] + bb, 0.f) * w2;
        }
#pragma unroll
        for (int off = 1; off < 16; off <<= 1) {
            p0 += __shfl_xor(p0, off);
            p1 += __shfl_xor(p1, off);
            p2 += __shfl_xor(p2, off);
            p3 += __shfl_xor(p3, off);
        }
        if (llo == 0) {
            int e = e_base + lhi * 4;
            out[e + 0] = p0 + b2;
            out[e + 1] = p1 + b2;
            out[e + 2] = p2 + b2;
            out[e + 3] = p3 + b2;
        }
    }
}

extern "C" void kernel_launch(void* const* d_in, const int* in_sizes, int n_in,
                              void* d_out, int out_size, void* d_ws, size_t ws_size,
                              hipStream_t stream) {
    const float* x   = (const float*)d_in[0];
    const int*   ei  = (const int*)d_in[1];
    const int*   eli = (const int*)d_in[2];
    const float* W1  = (const float*)d_in[3];
    const float* b1  = (const float*)d_in[4];
    const float* W2  = (const float*)d_in[5];
    const float* b2  = (const float*)d_in[6];
    const float* Wp1 = (const float*)d_in[7];
    const float* bp1 = (const float*)d_in[8];
    const float* Wp2 = (const float*)d_in[9];
    const float* bp2 = (const float*)d_in[10];
    float* out = (float*)d_out;

    char* w = (char*)d_ws;
    auto alloc = [&](size_t bytes) {
        char* p = w;
        w += (bytes + 255) & ~(size_t)255;
        return p;
    };
    float*          dinv   = (float*)alloc((size_t)NN * 4);
    int*            rowptr = (int*)alloc((size_t)(NN + 1) * 4);
    int*            histM  = (int*)alloc((size_t)NB * MSB * 4);
    unsigned*       tmp    = (unsigned*)alloc((size_t)EE * 4);
    int*            csr    = (int*)alloc((size_t)EE * 4);
    unsigned short* gbuf   = (unsigned short*)alloc((size_t)NN * 128 * 2);  // g1 then h2
    unsigned short* hbuf   = (unsigned short*)alloc((size_t)NN * 128 * 2);  // g2
    unsigned short* W1T    = (unsigned short*)alloc((size_t)128 * 128 * 2);
    unsigned short* W2T    = (unsigned short*)alloc((size_t)128 * 128 * 2);
    unsigned short* WpT    = (unsigned short*)alloc((size_t)128 * 256 * 2);

    const int* srcv = ei;       // row 0
    const int* dstv = ei + EE;  // row 1

    // weight pre-transpose (bf16 [n][k])
    convw_kernel<<<32, 256, 0, stream>>>(W1, W2, Wp1, W1T, W2T, WpT);

    // CSR build: multisplit by dst bucket, then per-bucket local CSR (+rowptr,+dinv)
    ms_hist_kernel<<<MSB, 256, 0, stream>>>(dstv, histM);
    ms_scan_kernel<<<1, 256, 0, stream>>>(histM, rowptr);
    ms_scatter_kernel<<<MSB, 256, 0, stream>>>(srcv, dstv, histM, tmp);
    bucket_csr_kernel<<<NB, 256, 0, stream>>>(tmp, histM, rowptr, dinv, csr);

    int nchunks = (NN + 63) / 64;  // 1563
    // g1 = dinv*(x@W1)
    gemm_mfma_kernel<<<1024, 256, 0, stream>>>(x, W1T, dinv, gbuf, nchunks);
    // fused: h1 = relu(dn*sum(g1)+b1); g2 = dinv*(h1@W2)
    agg1_gemm2_kernel<<<(NN + 127) / 128, 512, 0, stream>>>(gbuf, W2T, rowptr, csr, dinv, b1, hbuf);
    // h2 = dn*sum(g2)+b2 (row-major)
    agg2_kernel<<<(NN + 31) / 32, 512, 0, stream>>>(hbuf, rowptr, csr, dinv, b2, gbuf);
    // link scoring (reads row-major h2)
    link_mfma_kernel<<<512, 512, 0, stream>>>(gbuf, eli, WpT, bp1, Wp2, bp2, out);
}